// Round 13
// baseline (862.307 us; speedup 1.0000x reference)
//
#include <hip/hip_runtime.h>
#include <hip/hip_bf16.h>
#include <stdint.h>

#define Bv 128
#define Tv 512
#define Iv 64
#define Hv 512
#define Ov 64

typedef __attribute__((ext_vector_type(8))) short bv8;    // 8 bf16 for MFMA A/B
typedef __attribute__((ext_vector_type(4))) float fv4;    // MFMA C/D
typedef __attribute__((ext_vector_type(2))) float fv2;    // packed f32 pair
typedef __attribute__((ext_vector_type(4))) unsigned uv4;
typedef __attribute__((ext_vector_type(2))) unsigned uv2;
typedef __attribute__((ext_vector_type(8))) unsigned short usv8;

#define LOG2E 1.44269504f
#define TWOLOG2E 2.88539008f

static __device__ __forceinline__ unsigned short f2bf(float f) {
  unsigned u = __builtin_bit_cast(unsigned, f);
  u += 0x7fffu + ((u >> 16) & 1u);           // RNE
  return (unsigned short)(u >> 16);
}
static __device__ __forceinline__ float bf2f(unsigned short s) {
  return __builtin_bit_cast(float, ((unsigned)s) << 16);
}
static __device__ __forceinline__ fv2 pkfma(fv2 a, fv2 b, fv2 c) {
  return __builtin_elementwise_fma(a, b, c);   // v_pk_fma_f32
}

// async 16B/lane global -> LDS DMA (lane i's data lands at ldsbase + i*16;
// the GLOBAL source is per-lane, so source permutation shapes the LDS layout)
static __device__ __forceinline__ void dma16(const void* g, void* l) {
  __builtin_amdgcn_global_load_lds(
      (const __attribute__((address_space(1))) void*)g,
      (__attribute__((address_space(3))) void*)l, 16, 0, 0);
}

// Full 64-lane sum, result replicated in every lane. Fused single-instruction
// DPP adds for the 4 in-row levels.
static __device__ __forceinline__ float wave_red(float v) {
  float d;
  asm("v_add_f32_dpp %0, %1, %1 quad_perm:[1,0,3,2] row_mask:0xf bank_mask:0xf"
      : "=v"(d) : "v"(v)); v = d;
  asm("v_add_f32_dpp %0, %1, %1 quad_perm:[2,3,0,1] row_mask:0xf bank_mask:0xf"
      : "=v"(d) : "v"(v)); v = d;
  asm("v_add_f32_dpp %0, %1, %1 row_ror:4 row_mask:0xf bank_mask:0xf"
      : "=v"(d) : "v"(v)); v = d;
  asm("v_add_f32_dpp %0, %1, %1 row_ror:8 row_mask:0xf bank_mask:0xf"
      : "=v"(d) : "v"(v)); v = d;
  unsigned a = __builtin_bit_cast(unsigned, v);
  uv2 p = __builtin_amdgcn_permlane16_swap(a, a, false, false);
  v = __builtin_bit_cast(float, p[0]) + __builtin_bit_cast(float, p[1]);  // + v[lane^16]
  a = __builtin_bit_cast(unsigned, v);
  uv2 q = __builtin_amdgcn_permlane32_swap(a, a, false, false);
  v = __builtin_bit_cast(float, q[0]) + __builtin_bit_cast(float, q[1]);  // + v[lane^32]
  return v;
}

// ---------------------------------------------------------------------------
// K1: input projections. Stores NEGATED, log2e-scaled values:
//   irz slot = pack( -L*(iz), -L*(ir) ) bf16x2; ih = -2L*(ih) bf16.
// ---------------------------------------------------------------------------
__global__ __launch_bounds__(256) void proj_kernel(
    const float* __restrict__ u,
    const float* __restrict__ Wir, const float* __restrict__ bir,
    const float* __restrict__ Wiz, const float* __restrict__ biz,
    const float* __restrict__ Wih, const float* __restrict__ bih,
    unsigned* __restrict__ irz, unsigned short* __restrict__ ihb)
{
  __shared__ __align__(16) unsigned short As[64][72];  // bf16, padded stride
  const int bt0 = blockIdx.x * 64;
  const int h0b = blockIdx.y * 64;
  const int tid = threadIdx.x;
  {  // stage u tile f32 -> bf16 LDS
    const int r = tid >> 2, ksg = (tid & 3) * 16;
    const float* src = u + (size_t)(bt0 + r) * Iv + ksg;
    unsigned short tmp[16];
#pragma unroll
    for (int i = 0; i < 16; i += 4) {
      float4 v = *(const float4*)(src + i);
      tmp[i] = f2bf(v.x); tmp[i+1] = f2bf(v.y); tmp[i+2] = f2bf(v.z); tmp[i+3] = f2bf(v.w);
    }
    *(uv4*)&As[r][ksg]     = *(uv4*)&tmp[0];
    *(uv4*)&As[r][ksg + 8] = *(uv4*)&tmp[8];
  }
  __syncthreads();
  const int wave = tid >> 6, lane = tid & 63;
  const int n = lane & 15, q = lane >> 4;
  const int h = h0b + wave * 16 + n;
  const float* Wg[3] = {Wir, Wiz, Wih};
  const float SCL[3] = {-LOG2E, -LOG2E, -TWOLOG2E};
  bv8 bfrag[3][2];
#pragma unroll
  for (int g = 0; g < 3; ++g)
#pragma unroll
    for (int ks = 0; ks < 2; ++ks) {
      const float* wp = Wg[g] + (size_t)h * Iv + ks * 32 + q * 8;
      float4 w0 = *(const float4*)wp, w1 = *(const float4*)(wp + 4);
      const float s = SCL[g];
      bv8 f;
      f[0] = (short)f2bf(w0.x * s); f[1] = (short)f2bf(w0.y * s);
      f[2] = (short)f2bf(w0.z * s); f[3] = (short)f2bf(w0.w * s);
      f[4] = (short)f2bf(w1.x * s); f[5] = (short)f2bf(w1.y * s);
      f[6] = (short)f2bf(w1.z * s); f[7] = (short)f2bf(w1.w * s);
      bfrag[g][ks] = f;
    }
  const float bs0 = bir[h] * -LOG2E, bs1 = biz[h] * -LOG2E, bs2 = bih[h] * -TWOLOG2E;
#pragma unroll
  for (int sub = 0; sub < 4; ++sub) {
    bv8 a0 = *(const bv8*)&As[sub * 16 + n][q * 8];
    bv8 a1 = *(const bv8*)&As[sub * 16 + n][32 + q * 8];
    fv4 ar = {0.f,0.f,0.f,0.f}, az = {0.f,0.f,0.f,0.f}, ah = {0.f,0.f,0.f,0.f};
    ar = __builtin_amdgcn_mfma_f32_16x16x32_bf16(a0, bfrag[0][0], ar, 0, 0, 0);
    ar = __builtin_amdgcn_mfma_f32_16x16x32_bf16(a1, bfrag[0][1], ar, 0, 0, 0);
    az = __builtin_amdgcn_mfma_f32_16x16x32_bf16(a0, bfrag[1][0], az, 0, 0, 0);
    az = __builtin_amdgcn_mfma_f32_16x16x32_bf16(a1, bfrag[1][1], az, 0, 0, 0);
    ah = __builtin_amdgcn_mfma_f32_16x16x32_bf16(a0, bfrag[2][0], ah, 0, 0, 0);
    ah = __builtin_amdgcn_mfma_f32_16x16x32_bf16(a1, bfrag[2][1], ah, 0, 0, 0);
#pragma unroll
    for (int j = 0; j < 4; ++j) {
      const int row = bt0 + sub * 16 + q * 4 + j;   // C/D: col=lane&15, row=(lane>>4)*4+j
      const size_t slot = (size_t)row * Hv + h;
      irz[slot] = ((unsigned)f2bf(az[j] + bs1) << 16) | (unsigned)f2bf(ar[j] + bs0);
      ihb[slot] = f2bf(ah[j] + bs2);
    }
  }
}

// ---------------------------------------------------------------------------
// K2: the scan. 128 blocks x 1 wave; lane owns h = lane*8..+7.
// Matrices in LDS (48 KB). Per-step inputs streamed via async global_load_lds
// into a 2-deep ring, issued 2 steps ahead. FIXES vs R12:
//  (a) ring stored as 1KB chunks with PERMUTED DMA SOURCE (g + lane*32 [,+16])
//      so every consume read is b128 at chunk + lane*16 -> conflict-free.
//  (b) waits: first step vmcnt(5); steady-state vmcnt(7) = tolerate 2
//      in-flight stores + 5 next-step loads (never waits on stores).
// ---------------------------------------------------------------------------
#define OFF_NR 0
#define OFF_NZ 2048
#define OFF_NH 4096
#define OFF_MRZ0 6144
#define OFF_MRZ1 8192
#define OFF_MH2 10240
#define STREAM0 49152            // byte offset of ring buffer 0
#define STREAM_SZ 5120           // 5 x 1KB chunks: irz_lo irz_hi ih nz_lo nz_hi

__global__ __launch_bounds__(64, 1) void scan_kernel(
    const float* __restrict__ x0, const float* __restrict__ noise,
    const float* __restrict__ Nhr, const float* __restrict__ Mhr,
    const float* __restrict__ Nhz, const float* __restrict__ Mhz,
    const float* __restrict__ Nhh, const float* __restrict__ Mhh,
    unsigned* __restrict__ traj, const unsigned short* __restrict__ ihb,
    float* __restrict__ xlast)
{
  __shared__ __align__(16) float S[12288 + 2560];   // 48 KB matrices + 10 KB ring
  const int b = blockIdx.x, lane = threadIdx.x;
  const int h0 = lane * 8;
  const int xr = (lane & 7) * 4;
  const int lofs16 = lane * 16;    // consume-read offset within each 1KB chunk
  const int lofs32 = lane * 32;    // DMA source offset (permuted layout)

  int fo[8];
#pragma unroll
  for (int j = 0; j < 8; ++j) fo[j] = lane * 32 + ((j * 4) ^ xr);

#define LDQ(sec, j) (*(const fv4*)&S[(sec) + fo[j]])

  // matrices -> LDS (scaled, negated, interleaved; MH2 compact)
  {
    const float smr = -(1.0f / 512.0f) * LOG2E;
    const float smh = -(1.0f / 512.0f) * TWOLOG2E;
#pragma unroll
    for (int j = 0; j < 8; ++j) {
      *(fv4*)&S[OFF_NR + fo[j]] = *(const fv4*)(Nhr + (size_t)(h0 + j) * 4);
      *(fv4*)&S[OFF_NZ + fo[j]] = *(const fv4*)(Nhz + (size_t)(h0 + j) * 4);
      *(fv4*)&S[OFF_NH + fo[j]] = *(const fv4*)(Nhh + (size_t)(h0 + j) * 4);
      fv4 mr = *(const fv4*)(Mhr + (size_t)(h0 + j) * 4) * smr;
      fv4 mz = *(const fv4*)(Mhz + (size_t)(h0 + j) * 4) * smr;
      fv4 q0 = {mr[0], mz[0], mr[1], mz[1]};
      fv4 q1 = {mr[2], mz[2], mr[3], mz[3]};
      *(fv4*)&S[OFF_MRZ0 + fo[j]] = q0;
      *(fv4*)&S[OFF_MRZ1 + fo[j]] = q1;
    }
#pragma unroll
    for (int p = 0; p < 4; ++p) {
      fv4 a = *(const fv4*)(Mhh + (size_t)(h0 + 2 * p) * 4) * smh;
      fv4 c = *(const fv4*)(Mhh + (size_t)(h0 + 2 * p + 1) * 4) * smh;
      fv4 q0 = {a[0], c[0], a[1], c[1]};
      fv4 q1 = {a[2], c[2], a[3], c[3]};
      *(fv4*)&S[OFF_MH2 + fo[p]]     = q0;
      *(fv4*)&S[OFF_MH2 + fo[p + 4]] = q1;
    }
  }

  float x[8];
  {
    const float* xp = x0 + (size_t)b * Hv;
    fv4 a = *(const fv4*)(xp + h0);
    fv4 c = *(const fv4*)(xp + h0 + 4);
#pragma unroll
    for (int j = 0; j < 4; ++j) { x[j] = a[j]; x[j + 4] = c[j]; }
  }
  const unsigned* trajU = traj + (size_t)b * Tv * Hv;
  const unsigned short* ihU = ihb + (size_t)b * Tv * Hv;
  const float* noiseU = noise + (size_t)b * Hv;
  char* Sb = (char*)S;

  // issue one step's 5 DMA loads (permuted source -> lane*16 consume layout)
  auto ISSUE = [&](int sb, int t) {
    const char* g1 = (const char*)(trajU + (size_t)t * Hv) + lofs32;
    dma16(g1,      Sb + sb);             // irz h=8l..8l+3
    dma16(g1 + 16, Sb + sb + 1024);      // irz h=8l+4..8l+7
    const char* g2 = (const char*)(ihU + (size_t)t * Hv) + lofs16;
    dma16(g2,      Sb + sb + 2048);      // ih  h=8l..8l+7 (bf16)
    const char* g3 = (const char*)(noiseU + (size_t)t * (Bv * Hv)) + lofs32;
    dma16(g3,      Sb + sb + 3072);      // nz  h=8l..8l+3
    dma16(g3 + 16, Sb + sb + 4096);      // nz  h=8l+4..8l+7
  };

  auto STEP = [&](int sb, int t, bool first) {
    // P1: packed low-rank N projections for r,z (LDS matrices)
    fv2 sr01 = {0.f,0.f}, sr23 = {0.f,0.f}, sz01 = {0.f,0.f}, sz23 = {0.f,0.f};
#pragma unroll
    for (int j = 0; j < 8; ++j) {
      fv4 nrj = LDQ(OFF_NR, j), nzj = LDQ(OFF_NZ, j);
      fv2 xs = {x[j], x[j]};
      sr01 = pkfma(xs, fv2{nrj[0], nrj[1]}, sr01);
      sr23 = pkfma(xs, fv2{nrj[2], nrj[3]}, sr23);
      sz01 = pkfma(xs, fv2{nzj[0], nzj[1]}, sz01);
      sz23 = pkfma(xs, fv2{nzj[2], nzj[3]}, sz23);
    }
    // P2: 8 wave reductions
    float sr[4] = {sr01[0], sr01[1], sr23[0], sr23[1]};
    float sz[4] = {sz01[0], sz01[1], sz23[0], sz23[1]};
#pragma unroll
    for (int r = 0; r < 4; ++r) { sr[r] = wave_red(sr[r]); sz[r] = wave_red(sz[r]); }
    fv2 srz[4];
#pragma unroll
    for (int r = 0; r < 4; ++r) srz[r] = fv2{sr[r], sz[r]};
    // wait for this step's streamed inputs (issued 2 steps ago)
    if (first) { asm volatile("s_waitcnt vmcnt(5)" ::: "memory"); }
    else       { asm volatile("s_waitcnt vmcnt(7)" ::: "memory"); }
    __builtin_amdgcn_sched_barrier(0);
    uv4 irz0 = *(const uv4*)(Sb + sb + lofs16);
    uv4 irz1 = *(const uv4*)(Sb + sb + 1024 + lofs16);
    // P3: packed gate dots (LDS) + sigmoids (one rcp per r/z pair)
    float rxv[8], w02[8];
#pragma unroll
    for (int j = 0; j < 8; ++j) {
      fv4 q0 = LDQ(OFF_MRZ0, j), q1 = LDQ(OFF_MRZ1, j);
      fv2 h2 = fv2{q1[2], q1[3]} * srz[3];
      h2 = pkfma(fv2{q1[0], q1[1]}, srz[2], h2);
      h2 = pkfma(fv2{q0[2], q0[3]}, srz[1], h2);
      h2 = pkfma(fv2{q0[0], q0[1]}, srz[0], h2);
      unsigned w = (j < 4) ? irz0[j] : irz1[j - 4];
      float tr = h2[0] + __builtin_bit_cast(float, w << 16);
      float tz = h2[1] + __builtin_bit_cast(float, w & 0xffff0000u);
      float er = __builtin_amdgcn_exp2f(tr);       // = e^{-arg_r}
      float ez = __builtin_amdgcn_exp2f(tz);
      float Ar = 1.0f + er, Az = 1.0f + ez;
      float R = __builtin_amdgcn_rcpf(Ar * Az);
      rxv[j] = (R * Az) * x[j];                    // sigmoid_r * x
      w02[j] = fmaf(R * Ar, -0.2f, 0.2f);          // 0.2*(1-sigmoid_z)
    }
    // P4: packed N_h projection of r*x
    fv2 sh01 = {0.f,0.f}, sh23 = {0.f,0.f};
#pragma unroll
    for (int j = 0; j < 8; ++j) {
      fv4 nhj = LDQ(OFF_NH, j);
      fv2 xs = {rxv[j], rxv[j]};
      sh01 = pkfma(xs, fv2{nhj[0], nhj[1]}, sh01);
      sh23 = pkfma(xs, fv2{nhj[2], nhj[3]}, sh23);
    }
    // P5: 4 wave reductions + splat pairs
    fv2 sh2[4];
    {
      float s0 = wave_red(sh01[0]), s1 = wave_red(sh01[1]);
      float s2 = wave_red(sh23[0]), s3 = wave_red(sh23[1]);
      sh2[0] = fv2{s0, s0}; sh2[1] = fv2{s1, s1};
      sh2[2] = fv2{s2, s2}; sh2[3] = fv2{s3, s3};
    }
    // read ih, nz from the ring (all conflict-free lane*16 reads)
    usv8 ihv = *(const usv8*)(Sb + sb + 2048 + lofs16);
    fv4 nz0 = *(const fv4*)(Sb + sb + 3072 + lofs16);
    fv4 nz1 = *(const fv4*)(Sb + sb + 4096 + lofs16);
    // P6: packed hh per j-pair (LDS), tanh with shared rcp, state update
#pragma unroll
    for (int p = 0; p < 4; ++p) {
      fv4 q0 = *(const fv4*)&S[OFF_MH2 + fo[p]];
      fv4 q1 = *(const fv4*)&S[OFF_MH2 + fo[p + 4]];
      fv2 hh = fv2{q1[2], q1[3]} * sh2[3];
      hh = pkfma(fv2{q1[0], q1[1]}, sh2[2], hh);
      hh = pkfma(fv2{q0[2], q0[3]}, sh2[1], hh);
      hh = pkfma(fv2{q0[0], q0[1]}, sh2[0], hh);
      const int j0 = 2 * p, j1 = 2 * p + 1;
      float t0 = fminf(hh[0] + bf2f(ihv[j0]), 44.0f);   // = -2L*a, clamped
      float t1 = fminf(hh[1] + bf2f(ihv[j1]), 44.0f);
      float e0 = __builtin_amdgcn_exp2f(t0);
      float e1 = __builtin_amdgcn_exp2f(t1);
      float A0 = 1.0f + e0, A1 = 1.0f + e1;
      float R = __builtin_amdgcn_rcpf(A0 * A1);
      float g0 = (1.0f - e0) * A1 * R;                  // tanh
      float g1 = (1.0f - e1) * A0 * R;
      float d0 = g0 - x[j0], d1 = g1 - x[j1];
      float n0 = (j0 < 4) ? nz0[j0] : nz1[j0 - 4];
      float n1 = (j1 < 4) ? nz0[j1] : nz1[j1 - 4];
      x[j0] = fmaf(0.05f, n0, x[j0]);
      x[j0] = fmaf(w02[j0], d0, x[j0]);
      x[j1] = fmaf(0.05f, n1, x[j1]);
      x[j1] = fmaf(w02[j1], d1, x[j1]);
    }
    float* po = (float*)(trajU + (size_t)t * Hv);
    fv4 s0 = {x[0], x[1], x[2], x[3]}, s1 = {x[4], x[5], x[6], x[7]};
    *(fv4*)(po + h0) = s0;
    *(fv4*)(po + h0 + 4) = s1;
    // refill this ring slot for t+2 (clamped; tail refills redundant, in-bounds)
    int tn = t + 2 > Tv - 1 ? Tv - 1 : t + 2;
    ISSUE(sb, tn);
  };

  ISSUE(STREAM0, 0);
  ISSUE(STREAM0 + STREAM_SZ, 1);
  STEP(STREAM0, 0, true);
  for (int t = 1; t < Tv - 2; t += 2) {
    STEP(STREAM0 + STREAM_SZ, t, false);
    STEP(STREAM0, t + 1, false);
  }
  STEP(STREAM0 + STREAM_SZ, Tv - 1, false);
  {
    float* xp = xlast + (size_t)b * Hv;
    fv4 s0 = {x[0], x[1], x[2], x[3]}, s1 = {x[4], x[5], x[6], x[7]};
    *(fv4*)(xp + h0) = s0;
    *(fv4*)(xp + h0 + 4) = s1;
  }
#undef LDQ
}

// ---------------------------------------------------------------------------
// K3: output projection out[bt,o] = traj[bt,:] . W_out[o,:] + b_out[o]
// ---------------------------------------------------------------------------
__global__ __launch_bounds__(256) void outproj_kernel(
    const float* __restrict__ traj, const float* __restrict__ Wout,
    const float* __restrict__ bout, float* __restrict__ out)
{
  __shared__ __align__(16) unsigned short As[64][40];
  const int bt0 = blockIdx.x * 64;
  const int tid = threadIdx.x;
  const int wave = tid >> 6, lane = tid & 63;
  const int n = lane & 15, q = lane >> 4;
  const int o = wave * 16 + n;
  const float bo = bout[o];
  fv4 acc[4] = {{0.f,0.f,0.f,0.f},{0.f,0.f,0.f,0.f},{0.f,0.f,0.f,0.f},{0.f,0.f,0.f,0.f}};
  const int r = tid >> 2, ksg = (tid & 3) * 8;
  for (int ks = 0; ks < 16; ++ks) {
    __syncthreads();
    {
      const float* src = traj + (size_t)(bt0 + r) * Hv + ks * 32 + ksg;
      float4 v0 = *(const float4*)src, v1 = *(const float4*)(src + 4);
      unsigned short tmp[8];
      tmp[0] = f2bf(v0.x); tmp[1] = f2bf(v0.y); tmp[2] = f2bf(v0.z); tmp[3] = f2bf(v0.w);
      tmp[4] = f2bf(v1.x); tmp[5] = f2bf(v1.y); tmp[6] = f2bf(v1.z); tmp[7] = f2bf(v1.w);
      *(uv4*)&As[r][ksg] = *(uv4*)&tmp[0];
    }
    __syncthreads();
    const float* wp = Wout + (size_t)o * Hv + ks * 32 + q * 8;
    float4 w0 = *(const float4*)wp, w1 = *(const float4*)(wp + 4);
    bv8 bf;
    bf[0] = (short)f2bf(w0.x); bf[1] = (short)f2bf(w0.y);
    bf[2] = (short)f2bf(w0.z); bf[3] = (short)f2bf(w0.w);
    bf[4] = (short)f2bf(w1.x); bf[5] = (short)f2bf(w1.y);
    bf[6] = (short)f2bf(w1.z); bf[7] = (short)f2bf(w1.w);
#pragma unroll
    for (int sub = 0; sub < 4; ++sub) {
      bv8 af = *(const bv8*)&As[sub * 16 + n][q * 8];
      acc[sub] = __builtin_amdgcn_mfma_f32_16x16x32_bf16(af, bf, acc[sub], 0, 0, 0);
    }
  }
#pragma unroll
  for (int sub = 0; sub < 4; ++sub)
#pragma unroll
    for (int j = 0; j < 4; ++j) {
      const int row = bt0 + sub * 16 + q * 4 + j;
      out[(size_t)row * Ov + o] = acc[sub][j] + bo;
    }
}

// ---------------------------------------------------------------------------
extern "C" void kernel_launch(void* const* d_in, const int* in_sizes, int n_in,
                              void* d_out, int out_size, void* d_ws, size_t ws_size,
                              hipStream_t stream) {
  const float* u    = (const float*)d_in[0];
  const float* x0   = (const float*)d_in[1];
  const float* noise= (const float*)d_in[2];
  const float* Wir  = (const float*)d_in[3];
  const float* bir  = (const float*)d_in[4];
  const float* Wiz  = (const float*)d_in[5];
  const float* biz  = (const float*)d_in[6];
  const float* Wih  = (const float*)d_in[7];
  const float* bih  = (const float*)d_in[8];
  const float* Nhr  = (const float*)d_in[9];
  const float* Mhr  = (const float*)d_in[10];
  const float* Nhz  = (const float*)d_in[11];
  const float* Mhz  = (const float*)d_in[12];
  const float* Nhh  = (const float*)d_in[13];
  const float* Mhh  = (const float*)d_in[14];
  const float* Wout = (const float*)d_in[15];
  const float* bout = (const float*)d_in[16];

  float* out   = (float*)d_out;                    // [B,T,O]
  float* xlast = out + (size_t)Bv * Tv * Ov;       // [B,H]
  float* traj  = xlast + (size_t)Bv * Hv;          // [B,T,H]
  unsigned short* ihbuf = (unsigned short*)d_ws;   // [B*T*H] bf16 (64 MiB)

  proj_kernel<<<dim3(1024, 8, 1), 256, 0, stream>>>(
      u, Wir, bir, Wiz, biz, Wih, bih, (unsigned*)traj, ihbuf);
  scan_kernel<<<dim3(128, 1, 1), 64, 0, stream>>>(
      x0, noise, Nhr, Mhr, Nhz, Mhz, Nhh, Mhh, (unsigned*)traj, ihbuf, xlast);
  outproj_kernel<<<dim3(1024, 1, 1), 256, 0, stream>>>(traj, Wout, bout, out);
}

// Round 14
// 694.949 us; speedup vs baseline: 1.2408x; 1.2408x over previous
//
#include <hip/hip_runtime.h>
#include <hip/hip_bf16.h>
#include <stdint.h>

#define Bv 128
#define Tv 512
#define Iv 64
#define Hv 512
#define Ov 64

typedef __attribute__((ext_vector_type(8))) short bv8;    // 8 bf16 for MFMA A/B
typedef __attribute__((ext_vector_type(4))) float fv4;    // MFMA C/D
typedef __attribute__((ext_vector_type(4))) unsigned uv4;
typedef __attribute__((ext_vector_type(2))) unsigned uv2;
typedef __attribute__((ext_vector_type(4))) unsigned short usv4;

#define LOG2E 1.44269504f
#define TWOLOG2E 2.88539008f

static __device__ __forceinline__ unsigned short f2bf(float f) {
  unsigned u = __builtin_bit_cast(unsigned, f);
  u += 0x7fffu + ((u >> 16) & 1u);           // RNE
  return (unsigned short)(u >> 16);
}
static __device__ __forceinline__ float bf2f(unsigned short s) {
  return __builtin_bit_cast(float, ((unsigned)s) << 16);
}

// Full 64-lane sum, result replicated in every lane. Fused single-instruction
// DPP adds for the 4 in-row levels.
static __device__ __forceinline__ float wave_red(float v) {
  float d;
  asm("v_add_f32_dpp %0, %1, %1 quad_perm:[1,0,3,2] row_mask:0xf bank_mask:0xf"
      : "=v"(d) : "v"(v)); v = d;
  asm("v_add_f32_dpp %0, %1, %1 quad_perm:[2,3,0,1] row_mask:0xf bank_mask:0xf"
      : "=v"(d) : "v"(v)); v = d;
  asm("v_add_f32_dpp %0, %1, %1 row_ror:4 row_mask:0xf bank_mask:0xf"
      : "=v"(d) : "v"(v)); v = d;
  asm("v_add_f32_dpp %0, %1, %1 row_ror:8 row_mask:0xf bank_mask:0xf"
      : "=v"(d) : "v"(v)); v = d;
  unsigned a = __builtin_bit_cast(unsigned, v);
  uv2 p = __builtin_amdgcn_permlane16_swap(a, a, false, false);
  v = __builtin_bit_cast(float, p[0]) + __builtin_bit_cast(float, p[1]);  // + v[lane^16]
  a = __builtin_bit_cast(unsigned, v);
  uv2 q = __builtin_amdgcn_permlane32_swap(a, a, false, false);
  v = __builtin_bit_cast(float, q[0]) + __builtin_bit_cast(float, q[1]);  // + v[lane^32]
  return v;
}

// ---------------------------------------------------------------------------
// K1: input projections. Stores NEGATED, log2e-scaled values:
//   irz slot = pack( -L*(iz), -L*(ir) ) bf16x2; ih = -2L*(ih) bf16.
// ---------------------------------------------------------------------------
__global__ __launch_bounds__(256) void proj_kernel(
    const float* __restrict__ u,
    const float* __restrict__ Wir, const float* __restrict__ bir,
    const float* __restrict__ Wiz, const float* __restrict__ biz,
    const float* __restrict__ Wih, const float* __restrict__ bih,
    unsigned* __restrict__ irz, unsigned short* __restrict__ ihb)
{
  __shared__ __align__(16) unsigned short As[64][72];  // bf16, padded stride
  const int bt0 = blockIdx.x * 64;
  const int h0b = blockIdx.y * 64;
  const int tid = threadIdx.x;
  {  // stage u tile f32 -> bf16 LDS
    const int r = tid >> 2, ksg = (tid & 3) * 16;
    const float* src = u + (size_t)(bt0 + r) * Iv + ksg;
    unsigned short tmp[16];
#pragma unroll
    for (int i = 0; i < 16; i += 4) {
      float4 v = *(const float4*)(src + i);
      tmp[i] = f2bf(v.x); tmp[i+1] = f2bf(v.y); tmp[i+2] = f2bf(v.z); tmp[i+3] = f2bf(v.w);
    }
    *(uv4*)&As[r][ksg]     = *(uv4*)&tmp[0];
    *(uv4*)&As[r][ksg + 8] = *(uv4*)&tmp[8];
  }
  __syncthreads();
  const int wave = tid >> 6, lane = tid & 63;
  const int n = lane & 15, q = lane >> 4;
  const int h = h0b + wave * 16 + n;
  const float* Wg[3] = {Wir, Wiz, Wih};
  const float SCL[3] = {-LOG2E, -LOG2E, -TWOLOG2E};
  bv8 bfrag[3][2];
#pragma unroll
  for (int g = 0; g < 3; ++g)
#pragma unroll
    for (int ks = 0; ks < 2; ++ks) {
      const float* wp = Wg[g] + (size_t)h * Iv + ks * 32 + q * 8;
      float4 w0 = *(const float4*)wp, w1 = *(const float4*)(wp + 4);
      const float s = SCL[g];
      bv8 f;
      f[0] = (short)f2bf(w0.x * s); f[1] = (short)f2bf(w0.y * s);
      f[2] = (short)f2bf(w0.z * s); f[3] = (short)f2bf(w0.w * s);
      f[4] = (short)f2bf(w1.x * s); f[5] = (short)f2bf(w1.y * s);
      f[6] = (short)f2bf(w1.z * s); f[7] = (short)f2bf(w1.w * s);
      bfrag[g][ks] = f;
    }
  const float bs0 = bir[h] * -LOG2E, bs1 = biz[h] * -LOG2E, bs2 = bih[h] * -TWOLOG2E;
#pragma unroll
  for (int sub = 0; sub < 4; ++sub) {
    bv8 a0 = *(const bv8*)&As[sub * 16 + n][q * 8];
    bv8 a1 = *(const bv8*)&As[sub * 16 + n][32 + q * 8];
    fv4 ar = {0.f,0.f,0.f,0.f}, az = {0.f,0.f,0.f,0.f}, ah = {0.f,0.f,0.f,0.f};
    ar = __builtin_amdgcn_mfma_f32_16x16x32_bf16(a0, bfrag[0][0], ar, 0, 0, 0);
    ar = __builtin_amdgcn_mfma_f32_16x16x32_bf16(a1, bfrag[0][1], ar, 0, 0, 0);
    az = __builtin_amdgcn_mfma_f32_16x16x32_bf16(a0, bfrag[1][0], az, 0, 0, 0);
    az = __builtin_amdgcn_mfma_f32_16x16x32_bf16(a1, bfrag[1][1], az, 0, 0, 0);
    ah = __builtin_amdgcn_mfma_f32_16x16x32_bf16(a0, bfrag[2][0], ah, 0, 0, 0);
    ah = __builtin_amdgcn_mfma_f32_16x16x32_bf16(a1, bfrag[2][1], ah, 0, 0, 0);
#pragma unroll
    for (int j = 0; j < 4; ++j) {
      const int row = bt0 + sub * 16 + q * 4 + j;   // C/D: col=lane&15, row=(lane>>4)*4+j
      const size_t slot = (size_t)row * Hv + h;
      irz[slot] = ((unsigned)f2bf(az[j] + bs1) << 16) | (unsigned)f2bf(ar[j] + bs0);
      ihb[slot] = f2bf(ah[j] + bs2);
    }
  }
}

// ---------------------------------------------------------------------------
// K2: the scan. 128 blocks x 128 threads = 2 waves per batch; wave w owns
// h in [w*256, w*256+256), lane owns 4 h. Per-wave work HALVES vs the
// 1-wave version; waves run on 2 SIMDs of one CU and combine their rank-4
// partial sums twice per step through a tiny LDS exchange + __syncthreads
// (2-wave barrier, cheap). Matrices in LDS: per-thread slots at stride 20
// floats -> bank map (20t+4s)%32 covers 8 distinct bank-quads per beat
// (conflict-free b128 reads). Scalar dots; negated/log2e-folded weights so
// gates are raw exp2; shared rcp per sigmoid/tanh pair.
// ---------------------------------------------------------------------------
#define SECF 2560                    // floats per matrix section (128 thr x 20)
#define XB1 (6 * SECF)               // X1[2][8]
#define XB2 (6 * SECF + 16)          // X2[2][4]

struct Buf { uv4 irz; usv4 ih; fv4 nz; };

__global__ __launch_bounds__(128, 1) void scan_kernel(
    const float* __restrict__ x0, const float* __restrict__ noise,
    const float* __restrict__ Nhr, const float* __restrict__ Mhr,
    const float* __restrict__ Nhz, const float* __restrict__ Mhz,
    const float* __restrict__ Nhh, const float* __restrict__ Mhh,
    unsigned* __restrict__ traj, const unsigned short* __restrict__ ihb,
    float* __restrict__ xlast)
{
  __shared__ __align__(16) float S[6 * SECF + 32];   // 60KB matrices + exchange
  const int tid = threadIdx.x;
  const int w = tid >> 6, lane = tid & 63;
  const int b = blockIdx.x;
  const int h0 = w * 256 + lane * 4;                 // this thread's 4 h rows
  const int fb = tid * 20;                           // per-thread slot base (floats)

#define LDQ(sec, s) (*(const fv4*)&S[(sec) * SECF + fb + (s) * 4])

  // matrices -> LDS: thread owns rows h0..h0+3 of each. Sections:
  // 0=NR 1=NZ 2=NH 3=MR(*smr) 4=MZ(*smr) 5=MH(*smh)
  {
    const float smr = -(1.0f / 512.0f) * LOG2E;
    const float smh = -(1.0f / 512.0f) * TWOLOG2E;
#pragma unroll
    for (int j = 0; j < 4; ++j) {
      *(fv4*)&S[0 * SECF + fb + j * 4] = *(const fv4*)(Nhr + (size_t)(h0 + j) * 4);
      *(fv4*)&S[1 * SECF + fb + j * 4] = *(const fv4*)(Nhz + (size_t)(h0 + j) * 4);
      *(fv4*)&S[2 * SECF + fb + j * 4] = *(const fv4*)(Nhh + (size_t)(h0 + j) * 4);
      *(fv4*)&S[3 * SECF + fb + j * 4] = *(const fv4*)(Mhr + (size_t)(h0 + j) * 4) * smr;
      *(fv4*)&S[4 * SECF + fb + j * 4] = *(const fv4*)(Mhz + (size_t)(h0 + j) * 4) * smr;
      *(fv4*)&S[5 * SECF + fb + j * 4] = *(const fv4*)(Mhh + (size_t)(h0 + j) * 4) * smh;
    }
  }
  // each thread reads only its own slots; barrier only to order vs exchange use
  __syncthreads();

  float x[4];
  {
    fv4 a = *(const fv4*)(x0 + (size_t)b * Hv + h0);
#pragma unroll
    for (int j = 0; j < 4; ++j) x[j] = a[j];
  }
  const unsigned* trajU = traj + (size_t)b * Tv * Hv;
  const unsigned short* ihU = ihb + (size_t)b * Tv * Hv;
  const float* noiseU = noise + (size_t)b * Hv;

  Buf A, Bb;
  auto LOAD = [&](Buf& bf, int t) {
    bf.irz = *(const uv4*)(trajU + (size_t)t * Hv + h0);
    bf.ih  = *(const usv4*)(ihU + (size_t)t * Hv + h0);
    bf.nz  = *(const fv4*)(noiseU + (size_t)t * (Bv * Hv) + h0);
  };

  auto STEP = [&](const Buf& bf, int t) {
    // P1: partial rank-4 dots over this wave's 256 h
    float sr[4] = {0, 0, 0, 0}, sz[4] = {0, 0, 0, 0};
#pragma unroll
    for (int j = 0; j < 4; ++j) {
      fv4 nrj = LDQ(0, j), nzj = LDQ(1, j);
#pragma unroll
      for (int r = 0; r < 4; ++r) {
        sr[r] = fmaf(x[j], nrj[r], sr[r]);
        sz[r] = fmaf(x[j], nzj[r], sz[r]);
      }
    }
    // P2: in-wave trees + cross-wave exchange #1
#pragma unroll
    for (int r = 0; r < 4; ++r) { sr[r] = wave_red(sr[r]); sz[r] = wave_red(sz[r]); }
    if (lane == 0) {
      fv4 a = {sr[0], sr[1], sr[2], sr[3]}, c = {sz[0], sz[1], sz[2], sz[3]};
      *(fv4*)&S[XB1 + w * 8] = a;
      *(fv4*)&S[XB1 + w * 8 + 4] = c;
    }
    __syncthreads();
    {
      const float* o = &S[XB1 + (w ^ 1) * 8];
#pragma unroll
      for (int r = 0; r < 4; ++r) { sr[r] += o[r]; sz[r] += o[4 + r]; }
    }
    // P3: gate dots + sigmoids (shared rcp per r/z pair)
    float rxv[4], w02[4];
#pragma unroll
    for (int j = 0; j < 4; ++j) {
      fv4 mrj = LDQ(3, j), mzj = LDQ(4, j);
      float hr = fmaf(sr[3], mrj[3], fmaf(sr[2], mrj[2], fmaf(sr[1], mrj[1], sr[0] * mrj[0])));
      float hz = fmaf(sz[3], mzj[3], fmaf(sz[2], mzj[2], fmaf(sz[1], mzj[1], sz[0] * mzj[0])));
      unsigned wv = bf.irz[j];
      float tr = hr + __builtin_bit_cast(float, wv << 16);
      float tz = hz + __builtin_bit_cast(float, wv & 0xffff0000u);
      float er = __builtin_amdgcn_exp2f(tr);       // = e^{-arg_r}
      float ez = __builtin_amdgcn_exp2f(tz);
      float Ar = 1.0f + er, Az = 1.0f + ez;
      float R = __builtin_amdgcn_rcpf(Ar * Az);
      rxv[j] = (R * Az) * x[j];                    // sigmoid_r * x
      w02[j] = fmaf(R * Ar, -0.2f, 0.2f);          // 0.2*(1-sigmoid_z)
    }
    // P4: partial N_h dots
    float sh[4] = {0, 0, 0, 0};
#pragma unroll
    for (int j = 0; j < 4; ++j) {
      fv4 nhj = LDQ(2, j);
#pragma unroll
      for (int r = 0; r < 4; ++r) sh[r] = fmaf(rxv[j], nhj[r], sh[r]);
    }
    // P5: trees + exchange #2
#pragma unroll
    for (int r = 0; r < 4; ++r) sh[r] = wave_red(sh[r]);
    if (lane == 0) {
      fv4 a = {sh[0], sh[1], sh[2], sh[3]};
      *(fv4*)&S[XB2 + w * 4] = a;
    }
    __syncthreads();
    {
      const float* o = &S[XB2 + (w ^ 1) * 4];
#pragma unroll
      for (int r = 0; r < 4; ++r) sh[r] += o[r];
    }
    // P6: hh dots, tanh with shared rcp per pair, state update
#pragma unroll
    for (int p = 0; p < 2; ++p) {
      const int j0 = 2 * p, j1 = 2 * p + 1;
      fv4 m0 = LDQ(5, j0), m1 = LDQ(5, j1);
      float hh0 = fmaf(sh[3], m0[3], fmaf(sh[2], m0[2], fmaf(sh[1], m0[1], sh[0] * m0[0])));
      float hh1 = fmaf(sh[3], m1[3], fmaf(sh[2], m1[2], fmaf(sh[1], m1[1], sh[0] * m1[0])));
      float t0 = fminf(hh0 + bf2f(bf.ih[j0]), 44.0f);   // = -2L*a, clamped
      float t1 = fminf(hh1 + bf2f(bf.ih[j1]), 44.0f);
      float e0 = __builtin_amdgcn_exp2f(t0);
      float e1 = __builtin_amdgcn_exp2f(t1);
      float A0 = 1.0f + e0, A1 = 1.0f + e1;
      float R = __builtin_amdgcn_rcpf(A0 * A1);
      float g0 = (1.0f - e0) * A1 * R;                  // tanh
      float g1 = (1.0f - e1) * A0 * R;
      float d0 = g0 - x[j0], d1 = g1 - x[j1];
      x[j0] = fmaf(0.05f, bf.nz[j0], x[j0]);
      x[j0] = fmaf(w02[j0], d0, x[j0]);
      x[j1] = fmaf(0.05f, bf.nz[j1], x[j1]);
      x[j1] = fmaf(w02[j1], d1, x[j1]);
    }
    float* po = (float*)(trajU + (size_t)t * Hv);
    fv4 s0 = {x[0], x[1], x[2], x[3]};
    *(fv4*)(po + h0) = s0;
  };

  LOAD(A, 0);
  for (int t = 0; t < Tv; t += 2) {
    LOAD(Bb, t + 1);
    STEP(A, t);
    if (t + 2 < Tv) LOAD(A, t + 2);
    STEP(Bb, t + 1);
  }
  {
    fv4 s0 = {x[0], x[1], x[2], x[3]};
    *(fv4*)(xlast + (size_t)b * Hv + h0) = s0;
  }
#undef LDQ
}

// ---------------------------------------------------------------------------
// K3: output projection out[bt,o] = traj[bt,:] . W_out[o,:] + b_out[o]
// ---------------------------------------------------------------------------
__global__ __launch_bounds__(256) void outproj_kernel(
    const float* __restrict__ traj, const float* __restrict__ Wout,
    const float* __restrict__ bout, float* __restrict__ out)
{
  __shared__ __align__(16) unsigned short As[64][40];
  const int bt0 = blockIdx.x * 64;
  const int tid = threadIdx.x;
  const int wave = tid >> 6, lane = tid & 63;
  const int n = lane & 15, q = lane >> 4;
  const int o = wave * 16 + n;
  const float bo = bout[o];
  fv4 acc[4] = {{0.f,0.f,0.f,0.f},{0.f,0.f,0.f,0.f},{0.f,0.f,0.f,0.f},{0.f,0.f,0.f,0.f}};
  const int r = tid >> 2, ksg = (tid & 3) * 8;
  for (int ks = 0; ks < 16; ++ks) {
    __syncthreads();
    {
      const float* src = traj + (size_t)(bt0 + r) * Hv + ks * 32 + ksg;
      float4 v0 = *(const float4*)src, v1 = *(const float4*)(src + 4);
      unsigned short tmp[8];
      tmp[0] = f2bf(v0.x); tmp[1] = f2bf(v0.y); tmp[2] = f2bf(v0.z); tmp[3] = f2bf(v0.w);
      tmp[4] = f2bf(v1.x); tmp[5] = f2bf(v1.y); tmp[6] = f2bf(v1.z); tmp[7] = f2bf(v1.w);
      *(uv4*)&As[r][ksg] = *(uv4*)&tmp[0];
    }
    __syncthreads();
    const float* wp = Wout + (size_t)o * Hv + ks * 32 + q * 8;
    float4 w0 = *(const float4*)wp, w1 = *(const float4*)(wp + 4);
    bv8 bf;
    bf[0] = (short)f2bf(w0.x); bf[1] = (short)f2bf(w0.y);
    bf[2] = (short)f2bf(w0.z); bf[3] = (short)f2bf(w0.w);
    bf[4] = (short)f2bf(w1.x); bf[5] = (short)f2bf(w1.y);
    bf[6] = (short)f2bf(w1.z); bf[7] = (short)f2bf(w1.w);
#pragma unroll
    for (int sub = 0; sub < 4; ++sub) {
      bv8 af = *(const bv8*)&As[sub * 16 + n][q * 8];
      acc[sub] = __builtin_amdgcn_mfma_f32_16x16x32_bf16(af, bf, acc[sub], 0, 0, 0);
    }
  }
#pragma unroll
  for (int sub = 0; sub < 4; ++sub)
#pragma unroll
    for (int j = 0; j < 4; ++j) {
      const int row = bt0 + sub * 16 + q * 4 + j;
      out[(size_t)row * Ov + o] = acc[sub][j] + bo;
    }
}

// ---------------------------------------------------------------------------
extern "C" void kernel_launch(void* const* d_in, const int* in_sizes, int n_in,
                              void* d_out, int out_size, void* d_ws, size_t ws_size,
                              hipStream_t stream) {
  const float* u    = (const float*)d_in[0];
  const float* x0   = (const float*)d_in[1];
  const float* noise= (const float*)d_in[2];
  const float* Wir  = (const float*)d_in[3];
  const float* bir  = (const float*)d_in[4];
  const float* Wiz  = (const float*)d_in[5];
  const float* biz  = (const float*)d_in[6];
  const float* Wih  = (const float*)d_in[7];
  const float* bih  = (const float*)d_in[8];
  const float* Nhr  = (const float*)d_in[9];
  const float* Mhr  = (const float*)d_in[10];
  const float* Nhz  = (const float*)d_in[11];
  const float* Mhz  = (const float*)d_in[12];
  const float* Nhh  = (const float*)d_in[13];
  const float* Mhh  = (const float*)d_in[14];
  const float* Wout = (const float*)d_in[15];
  const float* bout = (const float*)d_in[16];

  float* out   = (float*)d_out;                    // [B,T,O]
  float* xlast = out + (size_t)Bv * Tv * Ov;       // [B,H]
  float* traj  = xlast + (size_t)Bv * Hv;          // [B,T,H]
  unsigned short* ihbuf = (unsigned short*)d_ws;   // [B*T*H] bf16 (64 MiB)

  proj_kernel<<<dim3(1024, 8, 1), 256, 0, stream>>>(
      u, Wir, bir, Wiz, biz, Wih, bih, (unsigned*)traj, ihbuf);
  scan_kernel<<<dim3(128, 1, 1), 128, 0, stream>>>(
      x0, noise, Nhr, Mhr, Nhz, Mhz, Nhh, Mhh, (unsigned*)traj, ihbuf, xlast);
  outproj_kernel<<<dim3(1024, 1, 1), 256, 0, stream>>>(traj, Wout, bout, out);
}